// Round 6
// baseline (10820.764 us; speedup 1.0000x reference)
//
#include <hip/hip_runtime.h>
#include <stdint.h>

#define Cc   16
#define HIDD 128
#define Bn   8
#define Hh   256
#define Ww   256
#define HW   (Hh * Ww)         // 65536
#define NPIX (Bn * HW)         // 524288
#define NSTEPS 32

typedef _Float16 half8 __attribute__((ext_vector_type(8)));
typedef __fp16 fp16x2 __attribute__((ext_vector_type(2)));
typedef float floatx16 __attribute__((ext_vector_type(16)));

// ---------------- JAX threefry2x32 (20 rounds), host+device ----------------
__host__ __device__ inline void threefry2x32(uint32_t k1, uint32_t k2,
                                             uint32_t x0, uint32_t x1,
                                             uint32_t& o0, uint32_t& o1) {
  const uint32_t ks2 = k1 ^ k2 ^ 0x1BD11BDAu;
  uint32_t v0 = x0 + k1;
  uint32_t v1 = x1 + k2;
#define ROTL32(x, n) (((x) << (n)) | ((x) >> (32 - (n))))
#define R4(a, b, c, d)                                    \
  { v0 += v1; v1 = ROTL32(v1, a); v1 ^= v0;               \
    v0 += v1; v1 = ROTL32(v1, b); v1 ^= v0;               \
    v0 += v1; v1 = ROTL32(v1, c); v1 ^= v0;               \
    v0 += v1; v1 = ROTL32(v1, d); v1 ^= v0; }
  R4(13, 15, 26, 6)   v0 += k2;  v1 += ks2 + 1u;
  R4(17, 29, 16, 24)  v0 += ks2; v1 += k1 + 2u;
  R4(13, 15, 26, 6)   v0 += k1;  v1 += k2 + 3u;
  R4(17, 29, 16, 24)  v0 += k2;  v1 += ks2 + 4u;
  R4(13, 15, 26, 6)   v0 += ks2; v1 += k1 + 5u;
#undef R4
#undef ROTL32
  o0 = v0;
  o1 = v1;
}

__device__ inline float fire_mask_f(uint32_t key0, uint32_t key1, uint32_t p) {
  uint32_t o0, o1;
  threefry2x32(key0, key1, 0u, p, o0, o1);
  const uint32_t bits = o0 ^ o1;
  const float u = __uint_as_float((bits >> 9) | 0x3f800000u) - 1.0f;
  return (u <= 0.5f) ? 1.0f : 0.0f;
}

// hidden-permutation: GEMM1 m-position (Mt, row 0..31) holds hidden unit
//   g = (2*Mt + u)*16 + 8*h8' + s'   (u,h8',s' decoded from row)
// so that GEMM1 C regs == GEMM2 B slots with no cross-lane movement.
__host__ __device__ inline int hid_of_row(int Mt, int row) {
  const int h8p = (row >> 2) & 1;
  const int r = (row & 3) + 4 * (row >> 3);
  const int u = r >> 3;
  const int sp = r & 7;
  return (2 * Mt + u) * 16 + 8 * h8p + sp;
}

// dx-row-position -> dx channel (so h8=0 owns ch3..7, h8=1 owns ch8..15)
__host__ __device__ inline int dxch_of_row(int mrow, int* valid) {
  if (mrow < 4)  { *valid = 1; return mrow + 3; }   // rows 0..3  -> ch 3..6
  if (mrow < 8)  { *valid = 1; return mrow + 4; }   // rows 4..7  -> ch 8..11
  if (mrow == 8) { *valid = 1; return 7; }          // row  8     -> ch 7
  if (mrow >= 12 && mrow < 16) { *valid = 1; return mrow; } // 12..15 -> ch 12..15
  *valid = 0; return 0;
}

// ---- prep: pack W0 / W1 into 32x32x16 A-fragment order (f16 hi/lo) ----
// W0 frags:   [Mt(4)][kt(3)][spl(2)][lane(64)][j(8)]  (12288 halfs)
//   value = split(wfc0[k][g]),  k = kt*16 + (lane>>5)*8 + j, g = hid_of_row
// W1 frags @12288: [kt2(8)][spl(2)][lane(64)][j(8)]   (8192 halfs)
//   value = split(wfc1[g][ch(mrow)]), g = kt2*16 + (lane>>5)*8 + j
__global__ __launch_bounds__(256) void k_prep(const float* __restrict__ wfc0,
                                              const float* __restrict__ wfc1,
                                              unsigned short* __restrict__ wf) {
  const int idx = blockIdx.x * 256 + threadIdx.x;
  float v = 0.f;
  int spl = 0;
  if (idx < 12288) {
    const int j = idx & 7;
    const int t = idx >> 3;
    const int lane = t & 63;
    const int t2 = t >> 6;
    spl = t2 & 1;
    const int fk = t2 >> 1;
    const int kt = fk % 3;
    const int Mt = fk / 3;
    const int row = lane & 31;
    const int k = kt * 16 + (lane >> 5) * 8 + j;
    const int g = hid_of_row(Mt, row);
    v = wfc0[k * HIDD + g];
  } else if (idx < 20480) {
    const int idx2 = idx - 12288;
    const int j = idx2 & 7;
    const int t = idx2 >> 3;
    const int lane = t & 63;
    const int t2 = t >> 6;
    spl = t2 & 1;
    const int kt2 = t2 >> 1;
    const int mrow = lane & 31;
    const int g = kt2 * 16 + (lane >> 5) * 8 + j;
    int valid;
    const int ch = dxch_of_row(mrow, &valid);
    v = valid ? wfc1[g * 16 + ch] : 0.f;
  } else {
    return;
  }
  const _Float16 hi = (_Float16)v;
  const _Float16 r = spl ? (_Float16)(v - (float)hi) : hi;
  union { _Float16 h; unsigned short s; } cv; cv.h = r;
  wf[idx] = cv.s;
}

// ---------------- NCHW -> NHWC state init ----------------
__global__ __launch_bounds__(256) void k_nchw_to_nhwc(const float* __restrict__ x,
                                                      float* __restrict__ st) {
  const int p = blockIdx.x * 256 + threadIdx.x;
  const int b = p >> 16;
  const int hw = p & 65535;
  const float* src = x + (size_t)b * (Cc * HW) + hw;
  float v[16];
#pragma unroll
  for (int c = 0; c < 16; c++) v[c] = src[(size_t)c * HW];
  float4* dst = (float4*)(st + (size_t)p * 16);
#pragma unroll
  for (int q = 0; q < 4; q++)
    dst[q] = make_float4(v[4 * q], v[4 * q + 1], v[4 * q + 2], v[4 * q + 3]);
}

// split helper: two f32 -> packed f16 hi (RTZ) + packed f16 lo (residual)
__device__ inline void split2(float a, float b, uint32_t& hi, uint32_t& lo) {
  union { fp16x2 v; uint32_t u; _Float16 h[2]; } ch;
  ch.v = __builtin_amdgcn_cvt_pkrtz(a, b);
  union { uint32_t u; _Float16 h[2]; } cl;
  cl.h[0] = (_Float16)(a - (float)ch.h[0]);
  cl.h[1] = (_Float16)(b - (float)ch.h[1]);
  hi = ch.u; lo = cl.u;
}

__device__ inline half8 mk8(uint32_t a, uint32_t b, uint32_t c, uint32_t d) {
  union { uint32_t u[4]; half8 h; } t;
  t.u[0] = a; t.u[1] = b; t.u[2] = c; t.u[3] = d;
  return t.h;
}

// ---------------- One NCA step ----------------
// Block = 512 threads (8 waves, 2 image rows). Each wave owns 64 pixels;
// thread (h8, ln31) computes channels [8*h8, 8*h8+8) for pixels
// p0 = wbase+ln31 and p1 = wbase+32+ln31. All MFMA operand layouts are
// permutation-matched so no cross-lane shuffles are needed anywhere.
__global__ __launch_bounds__(512, 4) void k_step(const float* __restrict__ in,
                                                 float* __restrict__ out,
                                                 const float* __restrict__ wp0,
                                                 const float* __restrict__ wp1,
                                                 const unsigned short* __restrict__ wf,
                                                 const float* __restrict__ bfc0,
                                                 uint32_t key0, uint32_t key1) {
  __shared__ __align__(16) unsigned short s_wf[20480];  // 40960 B

  const int tid = threadIdx.x;
  {
    const uint4* src = (const uint4*)wf;
    uint4* dst = (uint4*)s_wf;
#pragma unroll
    for (int i = 0; i < 5; i++) dst[tid + 512 * i] = src[tid + 512 * i];
  }
  __syncthreads();

  const int lane = tid & 63;
  const int h8 = lane >> 5;
  const int ln31 = lane & 31;
  const int wv = tid >> 6;

  const uint32_t pbase = (uint32_t)blockIdx.x * 512u;
  const uint32_t wbase = pbase + (uint32_t)wv * 64u;
  const int b = wbase >> 16;
  const int h = (wbase >> 8) & 255;
  const int w0 = (wbase & 255) + ln31;
  const int w1 = w0 + 32;

  // masks (one threefry per thread; pixel = wbase + lane)
  const float mOwn = fire_mask_f(key0, key1, wbase + (uint32_t)lane);
  const float mOth = __shfl_xor(mOwn, 32, 64);
  const float M0 = h8 ? mOth : mOwn;
  const float M1 = h8 ? mOwn : mOth;

  // ---- perception: channels cr = 8*h8 + i, two pixels ----
  const int rows[3] = { (h == 0) ? 1 : h - 1, h, (h == 255) ? 254 : h + 1 };
  const int c0s[3] = { (w0 == 0) ? 1 : w0 - 1, w0, w0 + 1 };            // w0<=223, no high clamp
  const int c1s[3] = { w1 - 1, w1, (w1 == 255) ? 254 : w1 + 1 };        // w1>=32, no low clamp

  float idv[2][8], cv0[2][8], cv1[2][8];
#pragma unroll
  for (int px = 0; px < 2; px++)
#pragma unroll
    for (int i = 0; i < 8; i++) { cv0[px][i] = 0.f; cv1[px][i] = 0.f; }

#pragma unroll
  for (int ty = 0; ty < 3; ty++) {
#pragma unroll
    for (int tx = 0; tx < 3; tx++) {
      const int tap = ty * 3 + tx;
      const float4 wq0a = *(const float4*)&wp0[tap * 16 + 8 * h8];
      const float4 wq0b = *(const float4*)&wp0[tap * 16 + 8 * h8 + 4];
      const float4 wq1a = *(const float4*)&wp1[tap * 16 + 8 * h8];
      const float4 wq1b = *(const float4*)&wp1[tap * 16 + 8 * h8 + 4];
      const int rbase = ((b << 8) + rows[ty]) << 8;
#pragma unroll
      for (int px = 0; px < 2; px++) {
        const int col = px ? c1s[tx] : c0s[tx];
        const float* bp = in + (size_t)(rbase + col) * 16 + 8 * h8;
        const float4 xa = *(const float4*)bp;
        const float4 xb = *(const float4*)(bp + 4);
        if (tap == 4) {
          idv[px][0] = xa.x; idv[px][1] = xa.y; idv[px][2] = xa.z; idv[px][3] = xa.w;
          idv[px][4] = xb.x; idv[px][5] = xb.y; idv[px][6] = xb.z; idv[px][7] = xb.w;
        }
        cv0[px][0] = fmaf(wq0a.x, xa.x, cv0[px][0]);
        cv0[px][1] = fmaf(wq0a.y, xa.y, cv0[px][1]);
        cv0[px][2] = fmaf(wq0a.z, xa.z, cv0[px][2]);
        cv0[px][3] = fmaf(wq0a.w, xa.w, cv0[px][3]);
        cv0[px][4] = fmaf(wq0b.x, xb.x, cv0[px][4]);
        cv0[px][5] = fmaf(wq0b.y, xb.y, cv0[px][5]);
        cv0[px][6] = fmaf(wq0b.z, xb.z, cv0[px][6]);
        cv0[px][7] = fmaf(wq0b.w, xb.w, cv0[px][7]);
        cv1[px][0] = fmaf(wq1a.x, xa.x, cv1[px][0]);
        cv1[px][1] = fmaf(wq1a.y, xa.y, cv1[px][1]);
        cv1[px][2] = fmaf(wq1a.z, xa.z, cv1[px][2]);
        cv1[px][3] = fmaf(wq1a.w, xa.w, cv1[px][3]);
        cv1[px][4] = fmaf(wq1b.x, xb.x, cv1[px][4]);
        cv1[px][5] = fmaf(wq1b.y, xb.y, cv1[px][5]);
        cv1[px][6] = fmaf(wq1b.z, xb.z, cv1[px][6]);
        cv1[px][7] = fmaf(wq1b.w, xb.w, cv1[px][7]);
      }
    }
  }

  // ---- per pixel-group phase: GEMM1 -> relu -> GEMM2 -> epilogue ----
#pragma unroll
  for (int ph = 0; ph < 2; ph++) {
    // B-frags: kt0 = identity, kt1 = conv0, kt2 = conv1; slot j = k offset
    uint32_t bh[3][4], bl[3][4];
#pragma unroll
    for (int d = 0; d < 4; d++) {
      split2(idv[ph][2 * d], idv[ph][2 * d + 1], bh[0][d], bl[0][d]);
      split2(cv0[ph][2 * d], cv0[ph][2 * d + 1], bh[1][d], bl[1][d]);
      split2(cv1[ph][2 * d], cv1[ph][2 * d + 1], bh[2][d], bl[2][d]);
    }

    floatx16 g2;
#pragma unroll
    for (int i = 0; i < 16; i++) g2[i] = 0.f;

#pragma unroll
    for (int Mt = 0; Mt < 4; Mt++) {
      // bias init: acc reg 8u+s' holds hidden g = (2Mt+u)*16 + 8*h8 + s'
      const float4 ba0 = *(const float4*)&bfc0[Mt * 32 + 8 * h8];
      const float4 ba1 = *(const float4*)&bfc0[Mt * 32 + 8 * h8 + 4];
      const float4 ba2 = *(const float4*)&bfc0[Mt * 32 + 16 + 8 * h8];
      const float4 ba3 = *(const float4*)&bfc0[Mt * 32 + 16 + 8 * h8 + 4];
      floatx16 acc = { ba0.x, ba0.y, ba0.z, ba0.w, ba1.x, ba1.y, ba1.z, ba1.w,
                       ba2.x, ba2.y, ba2.z, ba2.w, ba3.x, ba3.y, ba3.z, ba3.w };

#pragma unroll
      for (int kt = 0; kt < 3; kt++) {
        const half8 Ah = *(const half8*)&s_wf[((Mt * 3 + kt) * 2 + 0) * 512 + lane * 8];
        const half8 Al = *(const half8*)&s_wf[((Mt * 3 + kt) * 2 + 1) * 512 + lane * 8];
        const half8 Bh = mk8(bh[kt][0], bh[kt][1], bh[kt][2], bh[kt][3]);
        const half8 Bl = mk8(bl[kt][0], bl[kt][1], bl[kt][2], bl[kt][3]);
        acc = __builtin_amdgcn_mfma_f32_32x32x16_f16(Ah, Bh, acc, 0, 0, 0);
        acc = __builtin_amdgcn_mfma_f32_32x32x16_f16(Al, Bh, acc, 0, 0, 0);
        acc = __builtin_amdgcn_mfma_f32_32x32x16_f16(Ah, Bl, acc, 0, 0, 0);
      }

      // GEMM2: B slots (h8, j=s') = relu(acc[8u+s']) -- no shuffles
#pragma unroll
      for (int u = 0; u < 2; u++) {
        const int kt2 = 2 * Mt + u;
        const half8 W1h = *(const half8*)&s_wf[12288 + (kt2 * 2 + 0) * 512 + lane * 8];
        const half8 W1l = *(const half8*)&s_wf[12288 + (kt2 * 2 + 1) * 512 + lane * 8];
        float hv[8];
#pragma unroll
        for (int s = 0; s < 8; s++) hv[s] = fmaxf(acc[8 * u + s], 0.f);
        uint32_t hh[4], hl[4];
#pragma unroll
        for (int d = 0; d < 4; d++) split2(hv[2 * d], hv[2 * d + 1], hh[d], hl[d]);
        const half8 B2h = mk8(hh[0], hh[1], hh[2], hh[3]);
        const half8 B2l = mk8(hl[0], hl[1], hl[2], hl[3]);
        g2 = __builtin_amdgcn_mfma_f32_32x32x16_f16(W1h, B2h, g2, 0, 0, 0);
        g2 = __builtin_amdgcn_mfma_f32_32x32x16_f16(W1l, B2h, g2, 0, 0, 0);
        g2 = __builtin_amdgcn_mfma_f32_32x32x16_f16(W1h, B2l, g2, 0, 0, 0);
      }
    }

    // ---- epilogue: dx rows are permuted so this half-wave owns exactly
    // the channels it writes (h8=0: ch3..7 in regs 0..4; h8=1: ch8..15 in 0..7)
    const uint32_t p = wbase + (uint32_t)(ph * 32) + (uint32_t)ln31;
    const float M = ph ? M1 : M0;
    const float* xp = in + (size_t)p * 16 + 8 * h8;
    const float4 xa = *(const float4*)xp;
    const float4 xb = *(const float4*)(xp + 4);
    float4 oa, ob;
    oa.x = h8 ? fmaf(M, g2[0], xa.x) : xa.x;
    oa.y = h8 ? fmaf(M, g2[1], xa.y) : xa.y;
    oa.z = h8 ? fmaf(M, g2[2], xa.z) : xa.z;
    oa.w = fmaf(M, h8 ? g2[3] : g2[0], xa.w);
    ob.x = fmaf(M, h8 ? g2[4] : g2[1], xb.x);
    ob.y = fmaf(M, h8 ? g2[5] : g2[2], xb.y);
    ob.z = fmaf(M, h8 ? g2[6] : g2[3], xb.z);
    ob.w = fmaf(M, h8 ? g2[7] : g2[4], xb.w);
    float* op = out + (size_t)p * 16 + 8 * h8;
    *(float4*)op = oa;
    *(float4*)(op + 4) = ob;
  }
}

// ---------------- NHWC state -> (out slice, x_final NCHW) ----------------
__global__ __launch_bounds__(256) void k_nhwc_to_out(const float* __restrict__ st,
                                                     float* __restrict__ outp) {
  const int p = blockIdx.x * 256 + threadIdx.x;
  const int b = p >> 16;
  const int hw = p & 65535;
  const float4* src = (const float4*)(st + (size_t)p * 16);
  float v[16];
#pragma unroll
  for (int q = 0; q < 4; q++) {
    float4 t = src[q];
    v[4 * q] = t.x; v[4 * q + 1] = t.y; v[4 * q + 2] = t.z; v[4 * q + 3] = t.w;
  }
  float* xf = outp + NPIX;  // x_final region of d_out
#pragma unroll
  for (int c = 0; c < 16; c++) xf[(size_t)(b * 16 + c) * HW + hw] = v[c];
  outp[(size_t)b * HW + hw] = v[3];  // out = x_final[:, 3:4]
}

extern "C" void kernel_launch(void* const* d_in, const int* in_sizes, int n_in,
                              void* d_out, int out_size, void* d_ws, size_t ws_size,
                              hipStream_t stream) {
  const float* x    = (const float*)d_in[0];
  const float* wp0  = (const float*)d_in[1];
  const float* wp1  = (const float*)d_in[2];
  const float* wfc0 = (const float*)d_in[3];
  const float* bfc0 = (const float*)d_in[4];
  const float* wfc1 = (const float*)d_in[5];
  float* out = (float*)d_out;

  unsigned short* wf = (unsigned short*)d_ws;          // 20480 f16 (40960 B)
  float* S0 = (float*)((char*)d_ws + 65536);           // 33.5 MB scratch state
  float* S1 = out + NPIX;                              // x_final region as scratch

  // Step keys: foldlike split of key(42): keys[s] = threefry((0,42),(0,s))
  uint32_t k0[NSTEPS], k1[NSTEPS];
  for (int s = 0; s < NSTEPS; s++)
    threefry2x32(0u, 42u, 0u, (uint32_t)s, k0[s], k1[s]);

  hipLaunchKernelGGL(k_prep, dim3(80), dim3(256), 0, stream, wfc0, wfc1, wf);
  hipLaunchKernelGGL(k_nchw_to_nhwc, dim3(NPIX / 256), dim3(256), 0, stream, x, S0);
  float* cur = S0;
  float* nxt = S1;
  for (int s = 0; s < NSTEPS; s++) {
    hipLaunchKernelGGL(k_step, dim3(NPIX / 512), dim3(512), 0, stream,
                       cur, nxt, wp0, wp1, wf, bfc0, k0[s], k1[s]);
    float* t = cur; cur = nxt; nxt = t;
  }
  // 32 steps (even) -> final state back in S0
  hipLaunchKernelGGL(k_nhwc_to_out, dim3(NPIX / 256), dim3(256), 0, stream, cur, out);
}

// Round 7
// 1945.792 us; speedup vs baseline: 5.5611x; 5.5611x over previous
//
#include <hip/hip_runtime.h>
#include <stdint.h>

#define Cc   16
#define HIDD 128
#define Bn   8
#define Hh   256
#define Ww   256
#define HW   (Hh * Ww)         // 65536
#define NPIX (Bn * HW)         // 524288
#define NSTEPS 32

typedef _Float16 half8 __attribute__((ext_vector_type(8)));
typedef __fp16 fp16x2 __attribute__((ext_vector_type(2)));
typedef float floatx16 __attribute__((ext_vector_type(16)));

// ---------------- JAX threefry2x32 (20 rounds), host+device ----------------
__host__ __device__ inline void threefry2x32(uint32_t k1, uint32_t k2,
                                             uint32_t x0, uint32_t x1,
                                             uint32_t& o0, uint32_t& o1) {
  const uint32_t ks2 = k1 ^ k2 ^ 0x1BD11BDAu;
  uint32_t v0 = x0 + k1;
  uint32_t v1 = x1 + k2;
#define ROTL32(x, n) (((x) << (n)) | ((x) >> (32 - (n))))
#define R4(a, b, c, d)                                    \
  { v0 += v1; v1 = ROTL32(v1, a); v1 ^= v0;               \
    v0 += v1; v1 = ROTL32(v1, b); v1 ^= v0;               \
    v0 += v1; v1 = ROTL32(v1, c); v1 ^= v0;               \
    v0 += v1; v1 = ROTL32(v1, d); v1 ^= v0; }
  R4(13, 15, 26, 6)   v0 += k2;  v1 += ks2 + 1u;
  R4(17, 29, 16, 24)  v0 += ks2; v1 += k1 + 2u;
  R4(13, 15, 26, 6)   v0 += k1;  v1 += k2 + 3u;
  R4(17, 29, 16, 24)  v0 += k2;  v1 += ks2 + 4u;
  R4(13, 15, 26, 6)   v0 += ks2; v1 += k1 + 5u;
#undef R4
#undef ROTL32
  o0 = v0;
  o1 = v1;
}

__device__ inline float fire_mask_f(uint32_t key0, uint32_t key1, uint32_t p) {
  uint32_t o0, o1;
  threefry2x32(key0, key1, 0u, p, o0, o1);
  const uint32_t bits = o0 ^ o1;
  const float u = __uint_as_float((bits >> 9) | 0x3f800000u) - 1.0f;
  return (u <= 0.5f) ? 1.0f : 0.0f;
}

// hidden-permutation: GEMM1 m-position (Mt, row 0..31) holds hidden unit
//   g = (2*Mt + u)*16 + 8*h8' + s'   (u,h8',s' decoded from row)
// so that GEMM1 C regs == GEMM2 B slots with no cross-lane movement.
__host__ __device__ inline int hid_of_row(int Mt, int row) {
  const int h8p = (row >> 2) & 1;
  const int r = (row & 3) + 4 * (row >> 3);
  const int u = r >> 3;
  const int sp = r & 7;
  return (2 * Mt + u) * 16 + 8 * h8p + sp;
}

// dx-row-position -> dx channel (so h8=0 owns ch3..7, h8=1 owns ch8..15)
__host__ __device__ inline int dxch_of_row(int mrow, int* valid) {
  if (mrow < 4)  { *valid = 1; return mrow + 3; }   // rows 0..3  -> ch 3..6
  if (mrow < 8)  { *valid = 1; return mrow + 4; }   // rows 4..7  -> ch 8..11
  if (mrow == 8) { *valid = 1; return 7; }          // row  8     -> ch 7
  if (mrow >= 12 && mrow < 16) { *valid = 1; return mrow; } // 12..15 -> ch 12..15
  *valid = 0; return 0;
}

// ---- prep: pack W0 / W1 into 32x32x16 A-fragment order (f16 hi/lo) ----
__global__ __launch_bounds__(256) void k_prep(const float* __restrict__ wfc0,
                                              const float* __restrict__ wfc1,
                                              unsigned short* __restrict__ wf) {
  const int idx = blockIdx.x * 256 + threadIdx.x;
  float v = 0.f;
  int spl = 0;
  if (idx < 12288) {
    const int j = idx & 7;
    const int t = idx >> 3;
    const int lane = t & 63;
    const int t2 = t >> 6;
    spl = t2 & 1;
    const int fk = t2 >> 1;
    const int kt = fk % 3;
    const int Mt = fk / 3;
    const int row = lane & 31;
    const int k = kt * 16 + (lane >> 5) * 8 + j;
    const int g = hid_of_row(Mt, row);
    v = wfc0[k * HIDD + g];
  } else if (idx < 20480) {
    const int idx2 = idx - 12288;
    const int j = idx2 & 7;
    const int t = idx2 >> 3;
    const int lane = t & 63;
    const int t2 = t >> 6;
    spl = t2 & 1;
    const int kt2 = t2 >> 1;
    const int mrow = lane & 31;
    const int g = kt2 * 16 + (lane >> 5) * 8 + j;
    int valid;
    const int ch = dxch_of_row(mrow, &valid);
    v = valid ? wfc1[g * 16 + ch] : 0.f;
  } else {
    return;
  }
  const _Float16 hi = (_Float16)v;
  const _Float16 r = spl ? (_Float16)(v - (float)hi) : hi;
  union { _Float16 h; unsigned short s; } cv; cv.h = r;
  wf[idx] = cv.s;
}

// ---------------- NCHW -> NHWC state init ----------------
__global__ __launch_bounds__(256) void k_nchw_to_nhwc(const float* __restrict__ x,
                                                      float* __restrict__ st) {
  const int p = blockIdx.x * 256 + threadIdx.x;
  const int b = p >> 16;
  const int hw = p & 65535;
  const float* src = x + (size_t)b * (Cc * HW) + hw;
  float v[16];
#pragma unroll
  for (int c = 0; c < 16; c++) v[c] = src[(size_t)c * HW];
  float4* dst = (float4*)(st + (size_t)p * 16);
#pragma unroll
  for (int q = 0; q < 4; q++)
    dst[q] = make_float4(v[4 * q], v[4 * q + 1], v[4 * q + 2], v[4 * q + 3]);
}

// split helper: two f32 -> packed f16 hi (RTZ) + packed f16 lo (residual)
__device__ inline void split2(float a, float b, uint32_t& hi, uint32_t& lo) {
  union { fp16x2 v; uint32_t u; _Float16 h[2]; } ch;
  ch.v = __builtin_amdgcn_cvt_pkrtz(a, b);
  union { uint32_t u; _Float16 h[2]; } cl;
  cl.h[0] = (_Float16)(a - (float)ch.h[0]);
  cl.h[1] = (_Float16)(b - (float)ch.h[1]);
  hi = ch.u; lo = cl.u;
}

__device__ inline half8 mk8(uint32_t a, uint32_t b, uint32_t c, uint32_t d) {
  union { uint32_t u[4]; half8 h; } t;
  t.u[0] = a; t.u[1] = b; t.u[2] = c; t.u[3] = d;
  return t.h;
}

// ---------------- One NCA step ----------------
// Block = 512 threads (8 waves, 1 image row). Each wave owns 32 pixels;
// thread (h8, ln31) computes channels [8*h8, 8*h8+8) of pixel wbase+ln31
// and supplies exactly those values as B-operand k-slots (8*h8 + j).
// One pixel per thread -> ~95 live VGPRs, no spills, no shuffles at all.
__global__ __launch_bounds__(512, 2) void k_step(const float* __restrict__ in,
                                                 float* __restrict__ out,
                                                 const float* __restrict__ wp0,
                                                 const float* __restrict__ wp1,
                                                 const unsigned short* __restrict__ wf,
                                                 const float* __restrict__ bfc0,
                                                 uint32_t key0, uint32_t key1) {
  __shared__ __align__(16) unsigned short s_wf[20480];  // 40960 B

  const int tid = threadIdx.x;
  {
    const uint4* src = (const uint4*)wf;
    uint4* dst = (uint4*)s_wf;
#pragma unroll
    for (int i = 0; i < 5; i++) dst[tid + 512 * i] = src[tid + 512 * i];
  }
  __syncthreads();

  const int lane = tid & 63;
  const int h8 = lane >> 5;
  const int ln31 = lane & 31;
  const int wv = tid >> 6;

  const uint32_t p = (uint32_t)blockIdx.x * 256u + (uint32_t)wv * 32u + (uint32_t)ln31;
  const int b = p >> 16;
  const int h = (p >> 8) & 255;
  const int w = p & 255;

  // mask: every lane threefrys its own pixel (h8 halves duplicate -> no shuffle)
  const float M = fire_mask_f(key0, key1, p);

  // ---- perception: channels 8*h8 + i of pixel p ----
  const int rows[3] = { (h == 0) ? 1 : h - 1, h, (h == 255) ? 254 : h + 1 };
  const int cols[3] = { (w == 0) ? 1 : w - 1, w, (w == 255) ? 254 : w + 1 };

  float idv[8], cv0[8], cv1[8];
#pragma unroll
  for (int i = 0; i < 8; i++) { cv0[i] = 0.f; cv1[i] = 0.f; }

#pragma unroll
  for (int ty = 0; ty < 3; ty++) {
#pragma unroll
    for (int tx = 0; tx < 3; tx++) {
      const int tap = ty * 3 + tx;
      const float4 wq0a = *(const float4*)&wp0[tap * 16 + 8 * h8];
      const float4 wq0b = *(const float4*)&wp0[tap * 16 + 8 * h8 + 4];
      const float4 wq1a = *(const float4*)&wp1[tap * 16 + 8 * h8];
      const float4 wq1b = *(const float4*)&wp1[tap * 16 + 8 * h8 + 4];
      const int rbase = ((b << 8) + rows[ty]) << 8;
      const float* bp = in + (size_t)(rbase + cols[tx]) * 16 + 8 * h8;
      const float4 xa = *(const float4*)bp;
      const float4 xb = *(const float4*)(bp + 4);
      if (tap == 4) {
        idv[0] = xa.x; idv[1] = xa.y; idv[2] = xa.z; idv[3] = xa.w;
        idv[4] = xb.x; idv[5] = xb.y; idv[6] = xb.z; idv[7] = xb.w;
      }
      cv0[0] = fmaf(wq0a.x, xa.x, cv0[0]);
      cv0[1] = fmaf(wq0a.y, xa.y, cv0[1]);
      cv0[2] = fmaf(wq0a.z, xa.z, cv0[2]);
      cv0[3] = fmaf(wq0a.w, xa.w, cv0[3]);
      cv0[4] = fmaf(wq0b.x, xb.x, cv0[4]);
      cv0[5] = fmaf(wq0b.y, xb.y, cv0[5]);
      cv0[6] = fmaf(wq0b.z, xb.z, cv0[6]);
      cv0[7] = fmaf(wq0b.w, xb.w, cv0[7]);
      cv1[0] = fmaf(wq1a.x, xa.x, cv1[0]);
      cv1[1] = fmaf(wq1a.y, xa.y, cv1[1]);
      cv1[2] = fmaf(wq1a.z, xa.z, cv1[2]);
      cv1[3] = fmaf(wq1a.w, xa.w, cv1[3]);
      cv1[4] = fmaf(wq1b.x, xb.x, cv1[4]);
      cv1[5] = fmaf(wq1b.y, xb.y, cv1[5]);
      cv1[6] = fmaf(wq1b.z, xb.z, cv1[6]);
      cv1[7] = fmaf(wq1b.w, xb.w, cv1[7]);
    }
  }

  // ---- B-frags: kt0 = identity, kt1 = conv0, kt2 = conv1 ----
  uint32_t bh[3][4], bl[3][4];
#pragma unroll
  for (int d = 0; d < 4; d++) {
    split2(idv[2 * d], idv[2 * d + 1], bh[0][d], bl[0][d]);
    split2(cv0[2 * d], cv0[2 * d + 1], bh[1][d], bl[1][d]);
    split2(cv1[2 * d], cv1[2 * d + 1], bh[2][d], bl[2][d]);
  }

  floatx16 g2;
#pragma unroll
  for (int i = 0; i < 16; i++) g2[i] = 0.f;

#pragma unroll
  for (int Mt = 0; Mt < 4; Mt++) {
    // bias init: acc reg 8u+s' holds hidden g = (2Mt+u)*16 + 8*h8 + s'
    const float4 ba0 = *(const float4*)&bfc0[Mt * 32 + 8 * h8];
    const float4 ba1 = *(const float4*)&bfc0[Mt * 32 + 8 * h8 + 4];
    const float4 ba2 = *(const float4*)&bfc0[Mt * 32 + 16 + 8 * h8];
    const float4 ba3 = *(const float4*)&bfc0[Mt * 32 + 16 + 8 * h8 + 4];
    floatx16 acc = { ba0.x, ba0.y, ba0.z, ba0.w, ba1.x, ba1.y, ba1.z, ba1.w,
                     ba2.x, ba2.y, ba2.z, ba2.w, ba3.x, ba3.y, ba3.z, ba3.w };

#pragma unroll
    for (int kt = 0; kt < 3; kt++) {
      const half8 Ah = *(const half8*)&s_wf[((Mt * 3 + kt) * 2 + 0) * 512 + lane * 8];
      const half8 Al = *(const half8*)&s_wf[((Mt * 3 + kt) * 2 + 1) * 512 + lane * 8];
      const half8 Bh = mk8(bh[kt][0], bh[kt][1], bh[kt][2], bh[kt][3]);
      const half8 Bl = mk8(bl[kt][0], bl[kt][1], bl[kt][2], bl[kt][3]);
      acc = __builtin_amdgcn_mfma_f32_32x32x16_f16(Ah, Bh, acc, 0, 0, 0);
      acc = __builtin_amdgcn_mfma_f32_32x32x16_f16(Al, Bh, acc, 0, 0, 0);
      acc = __builtin_amdgcn_mfma_f32_32x32x16_f16(Ah, Bl, acc, 0, 0, 0);
    }

    // GEMM2: B slots (h8, j=s') = relu(acc[8u+s']) -- no shuffles
#pragma unroll
    for (int u = 0; u < 2; u++) {
      const int kt2 = 2 * Mt + u;
      const half8 W1h = *(const half8*)&s_wf[12288 + (kt2 * 2 + 0) * 512 + lane * 8];
      const half8 W1l = *(const half8*)&s_wf[12288 + (kt2 * 2 + 1) * 512 + lane * 8];
      float hv[8];
#pragma unroll
      for (int s = 0; s < 8; s++) hv[s] = fmaxf(acc[8 * u + s], 0.f);
      uint32_t hh[4], hl[4];
#pragma unroll
      for (int d = 0; d < 4; d++) split2(hv[2 * d], hv[2 * d + 1], hh[d], hl[d]);
      const half8 B2h = mk8(hh[0], hh[1], hh[2], hh[3]);
      const half8 B2l = mk8(hl[0], hl[1], hl[2], hl[3]);
      g2 = __builtin_amdgcn_mfma_f32_32x32x16_f16(W1h, B2h, g2, 0, 0, 0);
      g2 = __builtin_amdgcn_mfma_f32_32x32x16_f16(W1l, B2h, g2, 0, 0, 0);
      g2 = __builtin_amdgcn_mfma_f32_32x32x16_f16(W1h, B2l, g2, 0, 0, 0);
    }
  }

  // ---- epilogue: dx rows permuted so this half-wave owns exactly the
  // channels it writes (h8=0: ch3..7 in regs 0..4; h8=1: ch8..15 in 0..7)
  const float* xp = in + (size_t)p * 16 + 8 * h8;
  const float4 xa = *(const float4*)xp;
  const float4 xb = *(const float4*)(xp + 4);
  float4 oa, ob;
  oa.x = h8 ? fmaf(M, g2[0], xa.x) : xa.x;
  oa.y = h8 ? fmaf(M, g2[1], xa.y) : xa.y;
  oa.z = h8 ? fmaf(M, g2[2], xa.z) : xa.z;
  oa.w = fmaf(M, h8 ? g2[3] : g2[0], xa.w);
  ob.x = fmaf(M, h8 ? g2[4] : g2[1], xb.x);
  ob.y = fmaf(M, h8 ? g2[5] : g2[2], xb.y);
  ob.z = fmaf(M, h8 ? g2[6] : g2[3], xb.z);
  ob.w = fmaf(M, h8 ? g2[7] : g2[4], xb.w);
  float* op = out + (size_t)p * 16 + 8 * h8;
  *(float4*)op = oa;
  *(float4*)(op + 4) = ob;
}

// ---------------- NHWC state -> (out slice, x_final NCHW) ----------------
__global__ __launch_bounds__(256) void k_nhwc_to_out(const float* __restrict__ st,
                                                     float* __restrict__ outp) {
  const int p = blockIdx.x * 256 + threadIdx.x;
  const int b = p >> 16;
  const int hw = p & 65535;
  const float4* src = (const float4*)(st + (size_t)p * 16);
  float v[16];
#pragma unroll
  for (int q = 0; q < 4; q++) {
    float4 t = src[q];
    v[4 * q] = t.x; v[4 * q + 1] = t.y; v[4 * q + 2] = t.z; v[4 * q + 3] = t.w;
  }
  float* xf = outp + NPIX;  // x_final region of d_out
#pragma unroll
  for (int c = 0; c < 16; c++) xf[(size_t)(b * 16 + c) * HW + hw] = v[c];
  outp[(size_t)b * HW + hw] = v[3];  // out = x_final[:, 3:4]
}

extern "C" void kernel_launch(void* const* d_in, const int* in_sizes, int n_in,
                              void* d_out, int out_size, void* d_ws, size_t ws_size,
                              hipStream_t stream) {
  const float* x    = (const float*)d_in[0];
  const float* wp0  = (const float*)d_in[1];
  const float* wp1  = (const float*)d_in[2];
  const float* wfc0 = (const float*)d_in[3];
  const float* bfc0 = (const float*)d_in[4];
  const float* wfc1 = (const float*)d_in[5];
  float* out = (float*)d_out;

  unsigned short* wf = (unsigned short*)d_ws;          // 20480 f16 (40960 B)
  float* S0 = (float*)((char*)d_ws + 65536);           // 33.5 MB scratch state
  float* S1 = out + NPIX;                              // x_final region as scratch

  // Step keys: foldlike split of key(42): keys[s] = threefry((0,42),(0,s))
  uint32_t k0[NSTEPS], k1[NSTEPS];
  for (int s = 0; s < NSTEPS; s++)
    threefry2x32(0u, 42u, 0u, (uint32_t)s, k0[s], k1[s]);

  hipLaunchKernelGGL(k_prep, dim3(80), dim3(256), 0, stream, wfc0, wfc1, wf);
  hipLaunchKernelGGL(k_nchw_to_nhwc, dim3(NPIX / 256), dim3(256), 0, stream, x, S0);
  float* cur = S0;
  float* nxt = S1;
  for (int s = 0; s < NSTEPS; s++) {
    hipLaunchKernelGGL(k_step, dim3(NPIX / 256), dim3(512), 0, stream,
                       cur, nxt, wp0, wp1, wf, bfc0, k0[s], k1[s]);
    float* t = cur; cur = nxt; nxt = t;
  }
  // 32 steps (even) -> final state back in S0
  hipLaunchKernelGGL(k_nhwc_to_out, dim3(NPIX / 256), dim3(256), 0, stream, cur, out);
}